// Round 4
// baseline (350.215 us; speedup 1.0000x reference)
//
#include <hip/hip_runtime.h>
#include <math.h>

#define B 16
#define C 256
#define H 128
#define W 128
#define HW (H * W)      // 16384
#define HW4 (HW / 4)    // 4096 float4 chunks per image plane

typedef float vfloat4 __attribute__((ext_vector_type(4)));  // builtin-compatible

static __device__ __forceinline__ vfloat4 v4max(vfloat4 a, vfloat4 b) {
  vfloat4 r;
  r.x = fmaxf(a.x, b.x); r.y = fmaxf(a.y, b.y);
  r.z = fmaxf(a.z, b.z); r.w = fmaxf(a.w, b.w);
  return r;
}

// ---------------------------------------------------------------------------
// Kernel 1: channel-wise mean + max over C=256 for each (b, h, w).
// Each block owns 128 contiguous float4 chunks (2 KiB of pixels); its 4 waves
// each reduce a 64-channel quarter. Each thread handles TWO chunks (lane and
// lane+64) so every wave-channel step reads 2 KiB contiguous — fewer, longer
// DRAM streams than the 1 KiB version. Nontemporal loads keep L2 clean.
// feat output: [B, 2, H, W]  (plane 0 = mean, plane 1 = max)
// ---------------------------------------------------------------------------
__global__ __launch_bounds__(256, 4) void reduce_mean_max(
    const float* __restrict__ x, float* __restrict__ feat) {
  const int t    = threadIdx.x;
  const int lane = t & 63;
  const int cq   = t >> 6;                       // wave id = channel quarter
  const int chunkBase = blockIdx.x * 128;        // 128 chunks per block
  const int b    = chunkBase >> 12;              // 4096 chunks per image
  const int s4b  = chunkBase & (HW4 - 1);

  const vfloat4* xp =
      (const vfloat4*)x + (size_t)(b * C + cq * 64) * HW4 + s4b;

  vfloat4 sum0 = (vfloat4)(0.f), sum1 = (vfloat4)(0.f);
  vfloat4 mx0  = (vfloat4)(-INFINITY), mx1 = (vfloat4)(-INFINITY);
#pragma unroll 4
  for (int c = 0; c < 64; ++c) {
    const vfloat4* p = xp + (size_t)c * HW4;
    vfloat4 v0 = __builtin_nontemporal_load(&p[lane]);
    vfloat4 v1 = __builtin_nontemporal_load(&p[lane + 64]);
    sum0 += v0; sum1 += v1;
    mx0 = v4max(mx0, v0); mx1 = v4max(mx1, v1);
  }

  __shared__ vfloat4 s_sum[4][64][2];
  __shared__ vfloat4 s_max[4][64][2];
  s_sum[cq][lane][0] = sum0; s_sum[cq][lane][1] = sum1;
  s_max[cq][lane][0] = mx0;  s_max[cq][lane][1] = mx1;
  __syncthreads();

  // cq 0/1 -> mean plane (groups 0/1); cq 2/3 -> max plane (groups 0/1)
  const int g     = cq & 1;
  const int plane = cq >> 1;
  if (plane == 0) {
    vfloat4 a = s_sum[0][lane][g], b1 = s_sum[1][lane][g],
            c2 = s_sum[2][lane][g], d = s_sum[3][lane][g];
    vfloat4 mean = (a + b1 + c2 + d) * (1.0f / (float)C);
    ((vfloat4*)feat)[(size_t)(b * 2) * HW4 + s4b + g * 64 + lane] = mean;
  } else {
    vfloat4 a = s_max[0][lane][g], b1 = s_max[1][lane][g],
            c2 = s_max[2][lane][g], d = s_max[3][lane][g];
    vfloat4 m = v4max(v4max(a, b1), v4max(c2, d));
    ((vfloat4*)feat)[(size_t)(b * 2 + 1) * HW4 + s4b + g * 64 + lane] = m;
  }
}

// ---------------------------------------------------------------------------
// Kernel 2: 3x3 conv (2 in-ch -> 1 out-ch, zero pad 1) + sigmoid.
// One thread per output pixel; weights (18 floats) staged in LDS.
// feat is ~3 MB traffic -> L2-resident, trivial cost.
// ---------------------------------------------------------------------------
__global__ __launch_bounds__(256) void conv3x3_sigmoid(
    const float* __restrict__ feat, const float* __restrict__ wgt,
    float* __restrict__ out) {
  __shared__ float sw[18];
  if (threadIdx.x < 18) sw[threadIdx.x] = wgt[threadIdx.x];
  __syncthreads();

  const int idx = blockIdx.x * 256 + threadIdx.x;  // [0, 262144)
  const int b = idx >> 14;
  const int s = idx & (HW - 1);
  const int h = s >> 7;
  const int w = s & (W - 1);

  float acc = 0.f;
#pragma unroll
  for (int ci = 0; ci < 2; ++ci) {
    const float* f  = feat + (size_t)(b * 2 + ci) * HW;
    const float* kw = sw + ci * 9;
#pragma unroll
    for (int dh = -1; dh <= 1; ++dh) {
      const int hh = h + dh;
      if (hh < 0 || hh >= H) continue;
      const float* row = f + hh * W;
#pragma unroll
      for (int dw = -1; dw <= 1; ++dw) {
        const int ww = w + dw;
        if (ww < 0 || ww >= W) continue;
        acc += row[ww] * kw[(dh + 1) * 3 + (dw + 1)];
      }
    }
  }
  out[idx] = 1.f / (1.f + __expf(-acc));
}

extern "C" void kernel_launch(void* const* d_in, const int* in_sizes, int n_in,
                              void* d_out, int out_size, void* d_ws, size_t ws_size,
                              hipStream_t stream) {
  const float* x   = (const float*)d_in[0];   // [16, 256, 128, 128] fp32
  const float* wgt = (const float*)d_in[1];   // [1, 2, 3, 3] fp32
  float* out  = (float*)d_out;                // [16, 1, 128, 128] fp32
  float* feat = (float*)d_ws;                 // [16, 2, 128, 128] fp32 = 2 MB scratch

  // 65536 chunks / 128 per block = 512 blocks
  reduce_mean_max<<<512, 256, 0, stream>>>(x, feat);
  // 262144 outputs / 256 threads = 1024 blocks
  conv3x3_sigmoid<<<1024, 256, 0, stream>>>(feat, wgt, out);
}